// Round 5
// baseline (168.675 us; speedup 1.0000x reference)
//
#include <hip/hip_runtime.h>
#include <hip/hip_bf16.h>

// Joint network: out[b,t,u,o] = tanh(enc_proj[b,t,:] + dec_proj[b,u,:] + b1) @ W2 + b2
// B=8 T=256 U=64 D=512 H=1024 O=128.  All I/O fp32.
//
// tanh identity: with C2L = 2*log2(e),
//   tanh(x) = 1 - 2/(2^(C2L*x) + 1),  2^(C2L*(e+d+b1)) = Ep * Dp
// Ep/Dp precomputed fp16 in the projection epilogue. In the hot loop:
//   p = min(Ep*Dp + 1, 126)            (cap: err <= 0.016 where tanh ~ 1)
//   pairwise: rq = rcph(p0*p1); 1/p0 = p1*rq; 1/p1 = p0*rq   (4 rcph per 8)
//   A = 1 - 2*r
//
// ws: W1T f16 [1024][1024] @0 (2MiB) | W2T f16 [128][1024] @2MiB (256KiB)
//     Ep f16 [2048][1024] @2.25MiB (4MiB) | Dp f16 [512][1024] @6.25MiB (1MiB)

typedef _Float16 f16x8 __attribute__((ext_vector_type(8)));
typedef _Float16 f16x2 __attribute__((ext_vector_type(2)));
typedef float    f32x4 __attribute__((ext_vector_type(4)));

#define C2L 2.8853900817779268f

__device__ __forceinline__ float fast_exp2(float x) { return __builtin_amdgcn_exp2f(x); }

// v_cvt_pkrtz_f16_f32 returns __fp16x2 — bitcast to our _Float16x2
__device__ __forceinline__ f16x2 pk_cvt(float x, float y) {
    auto r = __builtin_amdgcn_cvt_pkrtz(x, y);
    union { decltype(r) a; f16x2 b; } c; c.a = r; return c.b;
}

// tanh on 8 packed f16 via pairwise reciprocal (4 rcph instead of 8).
// p = e*d + 1 in (1, inf); capped at 126 so q = p0*p1 <= 15876 keeps
// rq = rcph(q) >= 6.3e-5 in the f16 normal range (no denormal/overflow path).
__device__ __forceinline__ f16x8 tanh8(f16x8 e, f16x8 d) {
    const f16x8 one = {1,1,1,1,1,1,1,1};
    const f16x8 two = {2,2,2,2,2,2,2,2};
    const f16x8 cap = {126,126,126,126,126,126,126,126};
    union { f16x8 v; _Float16 s[8]; } p, r;
    p.v = e * d + one;                              // v_pk_fma_f16 x4
    p.v = __builtin_elementwise_min(p.v, cap);      // v_pk_min_f16 x4
    #pragma unroll
    for (int i = 0; i < 4; ++i) {
        _Float16 q  = p.s[2*i] * p.s[2*i+1];
        _Float16 rq = __builtin_amdgcn_rcph(q);
        r.s[2*i]   = p.s[2*i+1] * rq;               // = 1/p0
        r.s[2*i+1] = p.s[2*i]   * rq;               // = 1/p1
    }
    return one - two * r.v;                         // v_pk_fma_f16 x4
}

// async 16B global -> LDS (LDS dest is wave-uniform base + lane*16)
__device__ __forceinline__ void stage16(const void* g, void* l) {
    __builtin_amdgcn_global_load_lds(
        (const __attribute__((address_space(1))) unsigned int*)g,
        (__attribute__((address_space(3))) unsigned int*)l, 16, 0, 0);
}

// ---------------------------------------------------------------- transpose
// bx<32: W1 (1024x1024) -> W1T ; bx>=32: W2 (1024x128) -> W2T
// (R0 version — the 64x64/f16x8-store rewrite measured no better, R2.)
__global__ __launch_bounds__(1024) void transpose_both(
    const float* __restrict__ W1, const float* __restrict__ W2,
    _Float16* __restrict__ W1T, _Float16* __restrict__ W2T)
{
    __shared__ float tile[32][33];
    int bx = blockIdx.x;
    const float* src; _Float16* dst; int C, c0;
    if (bx < 32) { src = W1; dst = W1T; C = 1024; c0 = bx * 32; }
    else         { src = W2; dst = W2T; C = 128;  c0 = (bx - 32) * 32; }
    int r0 = blockIdx.y * 32;
    int tx = threadIdx.x, ty = threadIdx.y;
    tile[ty][tx] = src[(r0 + ty) * C + (c0 + tx)];
    __syncthreads();
    dst[(size_t)(c0 + ty) * 1024 + (r0 + tx)] = (_Float16)tile[tx][ty];
}

// ---------------------------------------------------------------- projections
// rows 0..2047 -> Ep = 2^(C2L*(enc@W1[:512] + b1)); rows 2048.. -> Dp (dec, no bias)
// v3 (kept, −20 us total in R4): 64x64 tile per block, W1T panel staged to
// LDS via global_load_lds, double-buffered BK=64, one barrier per tile; XOR
// chunk swizzle (0 bank conflicts); A rows prefetched one full tile deep in
// registers.
__global__ __launch_bounds__(256, 2) void proj_exp(
    const float* __restrict__ enc,     // [2048][512]
    const float* __restrict__ dec,     // [512][512]
    const _Float16* __restrict__ W1T,  // [1024][1024]
    const float* __restrict__ b1,      // [1024]
    _Float16* __restrict__ Ep,         // [2048][1024]
    _Float16* __restrict__ Dp)         // [512][1024]
{
    __shared__ _Float16 sB[2][64 * 64];   // 2 x 8 KiB: [n-col][k] swizzled

    const int K = 512;
    int tid  = threadIdx.x;
    int w    = tid >> 6, lane = tid & 63;
    int quad = lane >> 4, l15 = lane & 15;
    int m_base = blockIdx.y * 64;
    int n_base = blockIdx.x * 64;

    bool is_enc = (m_base < 2048);          // block-uniform (boundary 2048 = 32*64)
    int row = m_base + w * 16 + l15;
    const float* A = is_enc ? (enc + (size_t)row * K)
                            : (dec + (size_t)(row - 2048) * K);
    const _Float16* Bsrc = W1T + (is_enc ? 0 : 512);

    f32x4 acc[4] = {};

    // stage B tile 0 (64 cols x 64 k f16 = 8 KiB): 512 chunks of 16B, 2/thread
    #pragma unroll
    for (int i = 0; i < 2; ++i) {
        int c = i * 256 + tid;
        int r = c >> 3, kcs = c & 7;
        stage16(Bsrc + (size_t)(n_base + r) * 1024 + ((kcs ^ (r & 7)) << 3),
                &sB[0][(i * 256 + (tid & 0xC0)) * 8]);
    }
    // A prefetch for tile 0: lane's 16 floats at k = quad*8 (+32)
    float4 a0lo = *reinterpret_cast<const float4*>(A + quad * 8);
    float4 a0hi = *reinterpret_cast<const float4*>(A + quad * 8 + 4);
    float4 a1lo = *reinterpret_cast<const float4*>(A + 32 + quad * 8);
    float4 a1hi = *reinterpret_cast<const float4*>(A + 32 + quad * 8 + 4);

    for (int it = 0; it < 8; ++it) {
        __syncthreads();   // drains stage(it) — issued one full tile ago
        float4 n0lo, n0hi, n1lo, n1hi;
        if (it < 7) {
            int kb = (it + 1) * 64;
            _Float16* dst = sB[(it + 1) & 1];
            #pragma unroll
            for (int i = 0; i < 2; ++i) {
                int c = i * 256 + tid;
                int r = c >> 3, kcs = c & 7;
                stage16(Bsrc + (size_t)(n_base + r) * 1024 + kb + ((kcs ^ (r & 7)) << 3),
                        dst + (i * 256 + (tid & 0xC0)) * 8);
            }
            n0lo = *reinterpret_cast<const float4*>(A + kb + quad * 8);
            n0hi = *reinterpret_cast<const float4*>(A + kb + quad * 8 + 4);
            n1lo = *reinterpret_cast<const float4*>(A + kb + 32 + quad * 8);
            n1hi = *reinterpret_cast<const float4*>(A + kb + 32 + quad * 8 + 4);
        }
        const _Float16* sb = sB[it & 1];
        // ki2 = 0
        {
            union { f16x8 v; f16x2 h[4]; } a;
            a.h[0] = pk_cvt(a0lo.x, a0lo.y);
            a.h[1] = pk_cvt(a0lo.z, a0lo.w);
            a.h[2] = pk_cvt(a0hi.x, a0hi.y);
            a.h[3] = pk_cvt(a0hi.z, a0hi.w);
            int sw = ((0 * 4 + quad) ^ (l15 & 7)) << 3;
            #pragma unroll
            for (int f = 0; f < 4; ++f) {
                f16x8 bb = *reinterpret_cast<const f16x8*>(sb + (f * 16 + l15) * 64 + sw);
                acc[f] = __builtin_amdgcn_mfma_f32_16x16x32_f16(a.v, bb, acc[f], 0, 0, 0);
            }
        }
        // ki2 = 1
        {
            union { f16x8 v; f16x2 h[4]; } a;
            a.h[0] = pk_cvt(a1lo.x, a1lo.y);
            a.h[1] = pk_cvt(a1lo.z, a1lo.w);
            a.h[2] = pk_cvt(a1hi.x, a1hi.y);
            a.h[3] = pk_cvt(a1hi.z, a1hi.w);
            int sw = ((1 * 4 + quad) ^ (l15 & 7)) << 3;
            #pragma unroll
            for (int f = 0; f < 4; ++f) {
                f16x8 bb = *reinterpret_cast<const f16x8*>(sb + (f * 16 + l15) * 64 + sw);
                acc[f] = __builtin_amdgcn_mfma_f32_16x16x32_f16(a.v, bb, acc[f], 0, 0, 0);
            }
        }
        a0lo = n0lo; a0hi = n0hi; a1lo = n1lo; a1hi = n1hi;
    }

    #pragma unroll
    for (int f = 0; f < 4; ++f) {
        int col = n_base + f * 16 + l15;
        float bv = is_enc ? b1[col] : 0.0f;
        #pragma unroll
        for (int v = 0; v < 4; ++v) {
            int orow = m_base + w * 16 + quad * 4 + v;
            float val = fast_exp2(C2L * (acc[f][v] + bv));
            if (is_enc) Ep[(size_t)orow * 1024 + col] = (_Float16)val;
            else        Dp[(size_t)(orow - 2048) * 1024 + col] = (_Float16)val;
        }
    }
}

// ---------------------------------------------------------------- main fused
// Block = (b, t-quad): 4 t x 64 u x 128 o. 4 waves; wave w owns u-rows
// [16w,16w+16) for all 4 t.
// v4: NO W2T LDS staging. W2T is 256 KB (L2-resident per XCD) and the
// per-k-tile working set (16 KB) fits L1; all 8 waves on a CU read the SAME
// fragment addresses, so bb loads are L1 hits after first touch. This
// removes: 16 per-tile barriers (phase-locked stalls across both resident
// blocks), 960 global_load_lds chunks, the 32 KiB double buffer, and all
// LDS bb reads. R2 proved the identical 2KB-strided pattern is fine as
// direct global loads (Dp staging regressed). After the single sE barrier
// the kernel is barrier-free: vmem loads of iteration it+1 schedule under
// the MFMAs of iteration it, and the 2 blocks/CU decouple.
// Ep rows (4 x 2 KiB, HBM-cold, read-once) still staged to LDS; e-reads are
// broadcast ds_read_b128 (conflict-free). acc = 128 AGPRs, 2 blocks/CU.
__global__ __launch_bounds__(256, 2) void joint_main(
    const _Float16* __restrict__ Ep,   // [2048][1024]
    const _Float16* __restrict__ Dp,   // [512][1024]
    const _Float16* __restrict__ W2T,  // [128][1024]
    const float* __restrict__ b2,      // [128]
    float* __restrict__ out)           // [8][256][64][128]
{
    __shared__ _Float16 sE[4 * 1024];      // 8 KiB: 4 Ep rows

    int t0 = blockIdx.x * 4, b = blockIdx.y;
    int tid  = threadIdx.x;
    int w    = tid >> 6, lane = tid & 63;
    int quad = lane >> 4, l15 = lane & 15;
    int u0   = w * 16;

    const _Float16* epB = Ep + (size_t)(b * 256 + t0) * 1024;   // 4 contiguous rows
    const _Float16* dpr = Dp + (size_t)(b * 64 + u0 + l15) * 1024;
    const _Float16* w2r = W2T + (size_t)l15 * 1024;             // + f*16*1024 + k

    f32x4 acc[4][8] = {};   // [t][o-tile] = 128 AGPRs

    // stage 4 Ep rows (8 KiB, linear both sides): 512 chunks, 2 per thread
    #pragma unroll
    for (int i = 0; i < 2; ++i) {
        int c = i * 256 + tid;
        stage16(epB + c * 8, sE + (i * 256 + (tid & 0xC0)) * 8);
    }
    __syncthreads();   // the only barrier: drains the sE stage

    for (int it = 0; it < 16; ++it) {
        #pragma unroll
        for (int ki2 = 0; ki2 < 2; ++ki2) {
            int k = it * 64 + ki2 * 32 + quad * 8;
            f16x8 d8 = *reinterpret_cast<const f16x8*>(dpr + k);
            f16x8 A[4];
            #pragma unroll
            for (int tt = 0; tt < 4; ++tt) {
                // broadcast ds_read_b128 (same addr per quad group): conflict-free
                f16x8 e = *reinterpret_cast<const f16x8*>(sE + tt * 1024 + k);
                A[tt] = tanh8(e, d8);
            }
            #pragma unroll
            for (int f = 0; f < 8; ++f) {
                // direct from W2T: 16 rows x 64B sectors per instr, L1-hot
                f16x8 bb = *reinterpret_cast<const f16x8*>(w2r + f * 16 * 1024 + k);
                #pragma unroll
                for (int tt = 0; tt < 4; ++tt)
                    acc[tt][f] = __builtin_amdgcn_mfma_f32_16x16x32_f16(A[tt], bb, acc[tt][f], 0, 0, 0);
            }
        }
    }

    #pragma unroll
    for (int tt = 0; tt < 4; ++tt) {
        float* o = out + (size_t)(b * 256 + t0 + tt) * 64 * 128;
        #pragma unroll
        for (int f = 0; f < 8; ++f) {
            int oc = f * 16 + l15;
            float bv = b2[oc];
            #pragma unroll
            for (int v = 0; v < 4; ++v) {
                int u = u0 + quad * 4 + v;
                o[u * 128 + oc] = acc[tt][f][v] + bv;
            }
        }
    }
}

// ---------------------------------------------------------------- launch
extern "C" void kernel_launch(void* const* d_in, const int* in_sizes, int n_in,
                              void* d_out, int out_size, void* d_ws, size_t ws_size,
                              hipStream_t stream) {
    const float* enc = (const float*)d_in[0]; // [8][256][512]
    const float* dec = (const float*)d_in[1]; // [8][64][512]
    const float* W1  = (const float*)d_in[2]; // [1024][1024]
    const float* b1  = (const float*)d_in[3]; // [1024]
    const float* W2  = (const float*)d_in[4]; // [1024][128]
    const float* b2  = (const float*)d_in[5]; // [128]
    float* out = (float*)d_out;

    char* ws = (char*)d_ws;
    _Float16* W1T = (_Float16*)(ws);                               // 2 MiB
    _Float16* W2T = (_Float16*)(ws + (2u << 20));                  // 256 KiB
    _Float16* EpP = (_Float16*)(ws + (2u << 20) + (256u << 10));   // 4 MiB
    _Float16* DpP = (_Float16*)(ws + (6u << 20) + (256u << 10));   // 1 MiB

    transpose_both<<<dim3(36, 32), dim3(32, 32), 0, stream>>>(W1, W2, W1T, W2T);

    // fused projections + exp2 epilogue: M = 2048 (enc) + 512 (dec)
    proj_exp<<<dim3(16, 40), 256, 0, stream>>>(enc, dec, W1T, b1, EpP, DpP);

    joint_main<<<dim3(64, 8), 256, 0, stream>>>(EpP, DpP, W2T, b2, out);
}

// Round 6
// 143.199 us; speedup vs baseline: 1.1779x; 1.1779x over previous
//
#include <hip/hip_runtime.h>
#include <hip/hip_bf16.h>

// Joint network: out[b,t,u,o] = tanh(enc_proj[b,t,:] + dec_proj[b,u,:] + b1) @ W2 + b2
// B=8 T=256 U=64 D=512 H=1024 O=128.  All I/O fp32.
//
// tanh identity: with C2L = 2*log2(e),
//   tanh(x) = 1 - 2/(2^(C2L*x) + 1),  2^(C2L*(e+d+b1)) = Ep * Dp
// Ep/Dp precomputed fp16 in the projection epilogue. In the hot loop:
//   p = min(Ep*Dp + 1, 126)            (cap: err <= 0.016 where tanh ~ 1)
//   pairwise: rq = rcph(p0*p1); 1/p0 = p1*rq; 1/p1 = p0*rq   (4 rcph per 8)
//   A = 1 - 2*r
//
// ws: W1T f16 [1024][1024] @0 (2MiB) | W2T f16 [128][1024] @2MiB (256KiB)
//     Ep f16 [2048][1024] @2.25MiB (4MiB) | Dp f16 [512][1024] @6.25MiB (1MiB)

typedef _Float16 f16x8 __attribute__((ext_vector_type(8)));
typedef _Float16 f16x2 __attribute__((ext_vector_type(2)));
typedef float    f32x4 __attribute__((ext_vector_type(4)));

#define C2L 2.8853900817779268f

__device__ __forceinline__ float fast_exp2(float x) { return __builtin_amdgcn_exp2f(x); }

// v_cvt_pkrtz_f16_f32 returns __fp16x2 — bitcast to our _Float16x2
__device__ __forceinline__ f16x2 pk_cvt(float x, float y) {
    auto r = __builtin_amdgcn_cvt_pkrtz(x, y);
    union { decltype(r) a; f16x2 b; } c; c.a = r; return c.b;
}

// tanh on 8 packed f16 via pairwise reciprocal (4 rcph instead of 8).
// p = e*d + 1 in (1, inf); capped at 126 so q = p0*p1 <= 15876 keeps
// rq = rcph(q) >= 6.3e-5 in the f16 normal range (no denormal/overflow path).
__device__ __forceinline__ f16x8 tanh8(f16x8 e, f16x8 d) {
    const f16x8 one = {1,1,1,1,1,1,1,1};
    const f16x8 two = {2,2,2,2,2,2,2,2};
    const f16x8 cap = {126,126,126,126,126,126,126,126};
    union { f16x8 v; _Float16 s[8]; } p, r;
    p.v = e * d + one;                              // v_pk_fma_f16 x4
    p.v = __builtin_elementwise_min(p.v, cap);      // v_pk_min_f16 x4
    #pragma unroll
    for (int i = 0; i < 4; ++i) {
        _Float16 q  = p.s[2*i] * p.s[2*i+1];
        _Float16 rq = __builtin_amdgcn_rcph(q);
        r.s[2*i]   = p.s[2*i+1] * rq;               // = 1/p0
        r.s[2*i+1] = p.s[2*i]   * rq;               // = 1/p1
    }
    return one - two * r.v;                         // v_pk_fma_f16 x4
}

// async 16B global -> LDS (LDS dest is wave-uniform base + lane*16)
__device__ __forceinline__ void stage16(const void* g, void* l) {
    __builtin_amdgcn_global_load_lds(
        (const __attribute__((address_space(1))) unsigned int*)g,
        (__attribute__((address_space(3))) unsigned int*)l, 16, 0, 0);
}

// ---------------------------------------------------------------- transpose
// bx<32: W1 (1024x1024) -> W1T ; bx>=32: W2 (1024x128) -> W2T
// (R0 version — the 64x64/f16x8-store rewrite measured no better, R2.)
__global__ __launch_bounds__(1024) void transpose_both(
    const float* __restrict__ W1, const float* __restrict__ W2,
    _Float16* __restrict__ W1T, _Float16* __restrict__ W2T)
{
    __shared__ float tile[32][33];
    int bx = blockIdx.x;
    const float* src; _Float16* dst; int C, c0;
    if (bx < 32) { src = W1; dst = W1T; C = 1024; c0 = bx * 32; }
    else         { src = W2; dst = W2T; C = 128;  c0 = (bx - 32) * 32; }
    int r0 = blockIdx.y * 32;
    int tx = threadIdx.x, ty = threadIdx.y;
    tile[ty][tx] = src[(r0 + ty) * C + (c0 + tx)];
    __syncthreads();
    dst[(size_t)(c0 + ty) * 1024 + (r0 + tx)] = (_Float16)tile[tx][ty];
}

// ---------------------------------------------------------------- projections
// rows 0..2047 -> Ep = 2^(C2L*(enc@W1[:512] + b1)); rows 2048.. -> Dp (dec, no bias)
// v3 (kept, −20 us total in R4): 64x64 tile per block, W1T panel staged to
// LDS via global_load_lds, double-buffered BK=64, one barrier per tile; XOR
// chunk swizzle (0 bank conflicts); A rows prefetched one full tile deep in
// registers.
__global__ __launch_bounds__(256, 2) void proj_exp(
    const float* __restrict__ enc,     // [2048][512]
    const float* __restrict__ dec,     // [512][512]
    const _Float16* __restrict__ W1T,  // [1024][1024]
    const float* __restrict__ b1,      // [1024]
    _Float16* __restrict__ Ep,         // [2048][1024]
    _Float16* __restrict__ Dp)         // [512][1024]
{
    __shared__ _Float16 sB[2][64 * 64];   // 2 x 8 KiB: [n-col][k] swizzled

    const int K = 512;
    int tid  = threadIdx.x;
    int w    = tid >> 6, lane = tid & 63;
    int quad = lane >> 4, l15 = lane & 15;
    int m_base = blockIdx.y * 64;
    int n_base = blockIdx.x * 64;

    bool is_enc = (m_base < 2048);          // block-uniform (boundary 2048 = 32*64)
    int row = m_base + w * 16 + l15;
    const float* A = is_enc ? (enc + (size_t)row * K)
                            : (dec + (size_t)(row - 2048) * K);
    const _Float16* Bsrc = W1T + (is_enc ? 0 : 512);

    f32x4 acc[4] = {};

    // stage B tile 0 (64 cols x 64 k f16 = 8 KiB): 512 chunks of 16B, 2/thread
    #pragma unroll
    for (int i = 0; i < 2; ++i) {
        int c = i * 256 + tid;
        int r = c >> 3, kcs = c & 7;
        stage16(Bsrc + (size_t)(n_base + r) * 1024 + ((kcs ^ (r & 7)) << 3),
                &sB[0][(i * 256 + (tid & 0xC0)) * 8]);
    }
    // A prefetch for tile 0: lane's 16 floats at k = quad*8 (+32)
    float4 a0lo = *reinterpret_cast<const float4*>(A + quad * 8);
    float4 a0hi = *reinterpret_cast<const float4*>(A + quad * 8 + 4);
    float4 a1lo = *reinterpret_cast<const float4*>(A + 32 + quad * 8);
    float4 a1hi = *reinterpret_cast<const float4*>(A + 32 + quad * 8 + 4);

    for (int it = 0; it < 8; ++it) {
        __syncthreads();   // drains stage(it) — issued one full tile ago
        float4 n0lo, n0hi, n1lo, n1hi;
        if (it < 7) {
            int kb = (it + 1) * 64;
            _Float16* dst = sB[(it + 1) & 1];
            #pragma unroll
            for (int i = 0; i < 2; ++i) {
                int c = i * 256 + tid;
                int r = c >> 3, kcs = c & 7;
                stage16(Bsrc + (size_t)(n_base + r) * 1024 + kb + ((kcs ^ (r & 7)) << 3),
                        dst + (i * 256 + (tid & 0xC0)) * 8);
            }
            n0lo = *reinterpret_cast<const float4*>(A + kb + quad * 8);
            n0hi = *reinterpret_cast<const float4*>(A + kb + quad * 8 + 4);
            n1lo = *reinterpret_cast<const float4*>(A + kb + 32 + quad * 8);
            n1hi = *reinterpret_cast<const float4*>(A + kb + 32 + quad * 8 + 4);
        }
        const _Float16* sb = sB[it & 1];
        // ki2 = 0
        {
            union { f16x8 v; f16x2 h[4]; } a;
            a.h[0] = pk_cvt(a0lo.x, a0lo.y);
            a.h[1] = pk_cvt(a0lo.z, a0lo.w);
            a.h[2] = pk_cvt(a0hi.x, a0hi.y);
            a.h[3] = pk_cvt(a0hi.z, a0hi.w);
            int sw = ((0 * 4 + quad) ^ (l15 & 7)) << 3;
            #pragma unroll
            for (int f = 0; f < 4; ++f) {
                f16x8 bb = *reinterpret_cast<const f16x8*>(sb + (f * 16 + l15) * 64 + sw);
                acc[f] = __builtin_amdgcn_mfma_f32_16x16x32_f16(a.v, bb, acc[f], 0, 0, 0);
            }
        }
        // ki2 = 1
        {
            union { f16x8 v; f16x2 h[4]; } a;
            a.h[0] = pk_cvt(a1lo.x, a1lo.y);
            a.h[1] = pk_cvt(a1lo.z, a1lo.w);
            a.h[2] = pk_cvt(a1hi.x, a1hi.y);
            a.h[3] = pk_cvt(a1hi.z, a1hi.w);
            int sw = ((1 * 4 + quad) ^ (l15 & 7)) << 3;
            #pragma unroll
            for (int f = 0; f < 4; ++f) {
                f16x8 bb = *reinterpret_cast<const f16x8*>(sb + (f * 16 + l15) * 64 + sw);
                acc[f] = __builtin_amdgcn_mfma_f32_16x16x32_f16(a.v, bb, acc[f], 0, 0, 0);
            }
        }
        a0lo = n0lo; a0hi = n0hi; a1lo = n1lo; a1hi = n1hi;
    }

    #pragma unroll
    for (int f = 0; f < 4; ++f) {
        int col = n_base + f * 16 + l15;
        float bv = is_enc ? b1[col] : 0.0f;
        #pragma unroll
        for (int v = 0; v < 4; ++v) {
            int orow = m_base + w * 16 + quad * 4 + v;
            float val = fast_exp2(C2L * (acc[f][v] + bv));
            if (is_enc) Ep[(size_t)orow * 1024 + col] = (_Float16)val;
            else        Dp[(size_t)(orow - 2048) * 1024 + col] = (_Float16)val;
        }
    }
}

// ---------------------------------------------------------------- main fused
// v5: same block tile as R4-best (4 t x 64 u x 128 o, LDS-staged W2T,
// double-buffered BK=64, one barrier per tile — 47.8 us, best measured) but
// 512 threads / 8 waves: wave = (t-pair tp, u-quarter uq) owns 2t x 16u x
// 128o -> acc = 64 AGPR and per-wave VGPR shape = R0's proven ~60-reg code
// -> combined ~124 <= 128 -> 4 waves/SIMD (was 2 at 252 regs). R4's wall
// equaled the sum of the two resident waves' serial chains (zero overlap);
// doubling independent waves/SIMD is the latency-hiding fix that register
// pressure previously forbade. Staging traffic unchanged (still amortized
// over the full 4t block); LDS bb reads 2x (was ~18% busy -> ~36%, safe);
// tanh work still exactly partitioned. v4's lesson kept: bb MUST come from
// LDS (direct 2KB-strided global reads = 16 sectors/instr through TA, 81 us).
__global__ __launch_bounds__(512, 4) void joint_main(
    const _Float16* __restrict__ Ep,   // [2048][1024]
    const _Float16* __restrict__ Dp,   // [512][1024]
    const _Float16* __restrict__ W2T,  // [128][1024]
    const float* __restrict__ b2,      // [128]
    float* __restrict__ out)           // [8][256][64][128]
{
    __shared__ _Float16 sB[2][128 * 64];   // 2 x 16 KiB
    __shared__ _Float16 sE[4 * 1024];      // 8 KiB: 4 Ep rows

    int t0 = blockIdx.x * 4, b = blockIdx.y;
    int tid  = threadIdx.x;
    int w    = tid >> 6, lane = tid & 63;
    int quad = lane >> 4, l15 = lane & 15;
    int uq   = w & 3, tp = w >> 2;
    int u0   = uq * 16;

    const _Float16* epB = Ep + (size_t)(b * 256 + t0) * 1024;   // 4 contiguous rows
    const _Float16* dpr = Dp + (size_t)(b * 64 + u0 + l15) * 1024;

    f32x4 acc[2][8] = {};   // [t-within-pair][o-tile] = 64 AGPRs

    // stage 4 Ep rows (8 KiB, linear both sides): 512 chunks, 1 per thread
    stage16(epB + tid * 8, sE + (tid & 0x1C0) * 8);
    // stage W2T tile 0 into buf 0 (1024 chunks of 16B, 2 per thread)
    #pragma unroll
    for (int i = 0; i < 2; ++i) {
        int c = i * 512 + tid;
        int row = c >> 3, kcs = c & 7;
        stage16(W2T + row * 1024 + ((kcs ^ (row & 7)) << 3),
                &sB[0][(i * 512 + (tid & 0x1C0)) * 8]);
    }

    for (int it = 0; it < 16; ++it) {
        __syncthreads();   // drains stage(it) — issued one full tile ago (and sE at it=0)
        if (it < 15) {
            int kb = (it + 1) * 64;
            _Float16* dst = sB[(it + 1) & 1];
            #pragma unroll
            for (int i = 0; i < 2; ++i) {
                int c = i * 512 + tid;
                int row = c >> 3, kcs = c & 7;
                stage16(W2T + row * 1024 + kb + ((kcs ^ (row & 7)) << 3),
                        dst + (i * 512 + (tid & 0x1C0)) * 8);
            }
        }
        const _Float16* sb = sB[it & 1];
        #pragma unroll
        for (int ki2 = 0; ki2 < 2; ++ki2) {
            int k = it * 64 + ki2 * 32 + quad * 8;
            f16x8 d8 = *reinterpret_cast<const f16x8*>(dpr + k);
            f16x8 A[2];
            #pragma unroll
            for (int tt = 0; tt < 2; ++tt) {
                // broadcast ds_read_b128 (same addr per quad group): conflict-free
                f16x8 e = *reinterpret_cast<const f16x8*>(sE + (tp * 2 + tt) * 1024 + k);
                A[tt] = tanh8(e, d8);
            }
            int kc3 = ki2 * 4 + quad;
            int sw  = (kc3 ^ (l15 & 7)) << 3;        // uniform across f
            #pragma unroll
            for (int f = 0; f < 8; ++f) {
                f16x8 bb = *reinterpret_cast<const f16x8*>(
                    sb + (f * 16 + l15) * 64 + sw);
                #pragma unroll
                for (int tt = 0; tt < 2; ++tt)
                    acc[tt][f] = __builtin_amdgcn_mfma_f32_16x16x32_f16(A[tt], bb, acc[tt][f], 0, 0, 0);
            }
        }
    }

    #pragma unroll
    for (int tt = 0; tt < 2; ++tt) {
        float* o = out + (size_t)(b * 256 + t0 + tp * 2 + tt) * 64 * 128;
        #pragma unroll
        for (int f = 0; f < 8; ++f) {
            int oc = f * 16 + l15;
            float bv = b2[oc];
            #pragma unroll
            for (int v = 0; v < 4; ++v) {
                int u = u0 + quad * 4 + v;
                o[u * 128 + oc] = acc[tt][f][v] + bv;
            }
        }
    }
}

// ---------------------------------------------------------------- launch
extern "C" void kernel_launch(void* const* d_in, const int* in_sizes, int n_in,
                              void* d_out, int out_size, void* d_ws, size_t ws_size,
                              hipStream_t stream) {
    const float* enc = (const float*)d_in[0]; // [8][256][512]
    const float* dec = (const float*)d_in[1]; // [8][64][512]
    const float* W1  = (const float*)d_in[2]; // [1024][1024]
    const float* b1  = (const float*)d_in[3]; // [1024]
    const float* W2  = (const float*)d_in[4]; // [1024][128]
    const float* b2  = (const float*)d_in[5]; // [128]
    float* out = (float*)d_out;

    char* ws = (char*)d_ws;
    _Float16* W1T = (_Float16*)(ws);                               // 2 MiB
    _Float16* W2T = (_Float16*)(ws + (2u << 20));                  // 256 KiB
    _Float16* EpP = (_Float16*)(ws + (2u << 20) + (256u << 10));   // 4 MiB
    _Float16* DpP = (_Float16*)(ws + (6u << 20) + (256u << 10));   // 1 MiB

    transpose_both<<<dim3(36, 32), dim3(32, 32), 0, stream>>>(W1, W2, W1T, W2T);

    // fused projections + exp2 epilogue: M = 2048 (enc) + 512 (dec)
    proj_exp<<<dim3(16, 40), 256, 0, stream>>>(enc, dec, W1T, b1, EpP, DpP);

    // v5: 512-thread blocks, 8 waves (2 t-pair x 4 u-quarter), 4 waves/SIMD
    joint_main<<<dim3(64, 8), 512, 0, stream>>>(EpP, DpP, W2T, b2, out);
}

// Round 7
// 141.461 us; speedup vs baseline: 1.1924x; 1.0123x over previous
//
#include <hip/hip_runtime.h>
#include <hip/hip_bf16.h>

// Joint network: out[b,t,u,o] = tanh(enc_proj[b,t,:] + dec_proj[b,u,:] + b1) @ W2 + b2
// B=8 T=256 U=64 D=512 H=1024 O=128.  All I/O fp32.
//
// tanh identity: with C2L = 2*log2(e),
//   tanh(x) = 1 - 2/(2^(C2L*x) + 1),  2^(C2L*(e+d+b1)) = Ep * Dp
// Ep/Dp precomputed fp16 in the projection epilogue. In the hot loop:
//   p = min(Ep*Dp + 1, 126)            (cap: err <= 0.016 where tanh ~ 1)
//   pairwise: rq = rcph(p0*p1); 1/p0 = p1*rq; 1/p1 = p0*rq   (4 rcph per 8)
//   A = 1 - 2*r
//
// ws: W1T f16 [1024][1024] @0 (2MiB) | W2T f16 [128][1024] @2MiB (256KiB)
//     Ep f16 [2048][1024] @2.25MiB (4MiB) | Dp f16 [512][1024] @6.25MiB (1MiB)

typedef _Float16 f16x8 __attribute__((ext_vector_type(8)));
typedef _Float16 f16x2 __attribute__((ext_vector_type(2)));
typedef float    f32x4 __attribute__((ext_vector_type(4)));

#define C2L 2.8853900817779268f

__device__ __forceinline__ float fast_exp2(float x) { return __builtin_amdgcn_exp2f(x); }

// v_cvt_pkrtz_f16_f32 returns __fp16x2 — bitcast to our _Float16x2
__device__ __forceinline__ f16x2 pk_cvt(float x, float y) {
    auto r = __builtin_amdgcn_cvt_pkrtz(x, y);
    union { decltype(r) a; f16x2 b; } c; c.a = r; return c.b;
}

// tanh on 8 packed f16 via pairwise reciprocal (4 rcph instead of 8).
// p = e*d + 1 in (1, inf); capped at 126 so q = p0*p1 <= 15876 keeps
// rq = rcph(q) >= 6.3e-5 in the f16 normal range (no denormal/overflow path).
__device__ __forceinline__ f16x8 tanh8(f16x8 e, f16x8 d) {
    const f16x8 one = {1,1,1,1,1,1,1,1};
    const f16x8 two = {2,2,2,2,2,2,2,2};
    const f16x8 cap = {126,126,126,126,126,126,126,126};
    union { f16x8 v; _Float16 s[8]; } p, r;
    p.v = e * d + one;                              // v_pk_fma_f16 x4
    p.v = __builtin_elementwise_min(p.v, cap);      // v_pk_min_f16 x4
    #pragma unroll
    for (int i = 0; i < 4; ++i) {
        _Float16 q  = p.s[2*i] * p.s[2*i+1];
        _Float16 rq = __builtin_amdgcn_rcph(q);
        r.s[2*i]   = p.s[2*i+1] * rq;               // = 1/p0
        r.s[2*i+1] = p.s[2*i]   * rq;               // = 1/p1
    }
    return one - two * r.v;                         // v_pk_fma_f16 x4
}

// async 16B global -> LDS (LDS dest is wave-uniform base + lane*16)
__device__ __forceinline__ void stage16(const void* g, void* l) {
    __builtin_amdgcn_global_load_lds(
        (const __attribute__((address_space(1))) unsigned int*)g,
        (__attribute__((address_space(3))) unsigned int*)l, 16, 0, 0);
}

// ---------------------------------------------------------------- transpose
// bx<32: W1 (1024x1024) -> W1T ; bx>=32: W2 (1024x128) -> W2T
// (R0 version — rewrites measured neutral twice; leave alone.)
__global__ __launch_bounds__(1024) void transpose_both(
    const float* __restrict__ W1, const float* __restrict__ W2,
    _Float16* __restrict__ W1T, _Float16* __restrict__ W2T)
{
    __shared__ float tile[32][33];
    int bx = blockIdx.x;
    const float* src; _Float16* dst; int C, c0;
    if (bx < 32) { src = W1; dst = W1T; C = 1024; c0 = bx * 32; }
    else         { src = W2; dst = W2T; C = 128;  c0 = (bx - 32) * 32; }
    int r0 = blockIdx.y * 32;
    int tx = threadIdx.x, ty = threadIdx.y;
    tile[ty][tx] = src[(r0 + ty) * C + (c0 + tx)];
    __syncthreads();
    dst[(size_t)(c0 + ty) * 1024 + (r0 + tx)] = (_Float16)tile[tx][ty];
}

// ---------------------------------------------------------------- projections
// rows 0..2047 -> Ep = 2^(C2L*(enc@W1[:512] + b1)); rows 2048.. -> Dp (dec, no bias)
// v3 structure (kept, −20 us total in R4) + launch_bounds(256,4): forces
// VGPR <= 128 so all 640 blocks fit one occupancy round (4 blocks/CU,
// LDS 4x16K = 64K). If VGPR was already <=128 this is a no-op.
__global__ __launch_bounds__(256, 4) void proj_exp(
    const float* __restrict__ enc,     // [2048][512]
    const float* __restrict__ dec,     // [512][512]
    const _Float16* __restrict__ W1T,  // [1024][1024]
    const float* __restrict__ b1,      // [1024]
    _Float16* __restrict__ Ep,         // [2048][1024]
    _Float16* __restrict__ Dp)         // [512][1024]
{
    __shared__ _Float16 sB[2][64 * 64];   // 2 x 8 KiB: [n-col][k] swizzled

    const int K = 512;
    int tid  = threadIdx.x;
    int w    = tid >> 6, lane = tid & 63;
    int quad = lane >> 4, l15 = lane & 15;
    int m_base = blockIdx.y * 64;
    int n_base = blockIdx.x * 64;

    bool is_enc = (m_base < 2048);          // block-uniform (boundary 2048 = 32*64)
    int row = m_base + w * 16 + l15;
    const float* A = is_enc ? (enc + (size_t)row * K)
                            : (dec + (size_t)(row - 2048) * K);
    const _Float16* Bsrc = W1T + (is_enc ? 0 : 512);

    f32x4 acc[4] = {};

    // stage B tile 0 (64 cols x 64 k f16 = 8 KiB): 512 chunks of 16B, 2/thread
    #pragma unroll
    for (int i = 0; i < 2; ++i) {
        int c = i * 256 + tid;
        int r = c >> 3, kcs = c & 7;
        stage16(Bsrc + (size_t)(n_base + r) * 1024 + ((kcs ^ (r & 7)) << 3),
                &sB[0][(i * 256 + (tid & 0xC0)) * 8]);
    }
    // A prefetch for tile 0: lane's 16 floats at k = quad*8 (+32)
    float4 a0lo = *reinterpret_cast<const float4*>(A + quad * 8);
    float4 a0hi = *reinterpret_cast<const float4*>(A + quad * 8 + 4);
    float4 a1lo = *reinterpret_cast<const float4*>(A + 32 + quad * 8);
    float4 a1hi = *reinterpret_cast<const float4*>(A + 32 + quad * 8 + 4);

    for (int it = 0; it < 8; ++it) {
        __syncthreads();   // drains stage(it) — issued one full tile ago
        float4 n0lo, n0hi, n1lo, n1hi;
        if (it < 7) {
            int kb = (it + 1) * 64;
            _Float16* dst = sB[(it + 1) & 1];
            #pragma unroll
            for (int i = 0; i < 2; ++i) {
                int c = i * 256 + tid;
                int r = c >> 3, kcs = c & 7;
                stage16(Bsrc + (size_t)(n_base + r) * 1024 + kb + ((kcs ^ (r & 7)) << 3),
                        dst + (i * 256 + (tid & 0xC0)) * 8);
            }
            n0lo = *reinterpret_cast<const float4*>(A + kb + quad * 8);
            n0hi = *reinterpret_cast<const float4*>(A + kb + quad * 8 + 4);
            n1lo = *reinterpret_cast<const float4*>(A + kb + 32 + quad * 8);
            n1hi = *reinterpret_cast<const float4*>(A + kb + 32 + quad * 8 + 4);
        }
        const _Float16* sb = sB[it & 1];
        // ki2 = 0
        {
            union { f16x8 v; f16x2 h[4]; } a;
            a.h[0] = pk_cvt(a0lo.x, a0lo.y);
            a.h[1] = pk_cvt(a0lo.z, a0lo.w);
            a.h[2] = pk_cvt(a0hi.x, a0hi.y);
            a.h[3] = pk_cvt(a0hi.z, a0hi.w);
            int sw = ((0 * 4 + quad) ^ (l15 & 7)) << 3;
            #pragma unroll
            for (int f = 0; f < 4; ++f) {
                f16x8 bb = *reinterpret_cast<const f16x8*>(sb + (f * 16 + l15) * 64 + sw);
                acc[f] = __builtin_amdgcn_mfma_f32_16x16x32_f16(a.v, bb, acc[f], 0, 0, 0);
            }
        }
        // ki2 = 1
        {
            union { f16x8 v; f16x2 h[4]; } a;
            a.h[0] = pk_cvt(a1lo.x, a1lo.y);
            a.h[1] = pk_cvt(a1lo.z, a1lo.w);
            a.h[2] = pk_cvt(a1hi.x, a1hi.y);
            a.h[3] = pk_cvt(a1hi.z, a1hi.w);
            int sw = ((1 * 4 + quad) ^ (l15 & 7)) << 3;
            #pragma unroll
            for (int f = 0; f < 4; ++f) {
                f16x8 bb = *reinterpret_cast<const f16x8*>(sb + (f * 16 + l15) * 64 + sw);
                acc[f] = __builtin_amdgcn_mfma_f32_16x16x32_f16(a.v, bb, acc[f], 0, 0, 0);
            }
        }
        a0lo = n0lo; a0hi = n0hi; a1lo = n1lo; a1hi = n1hi;
    }

    #pragma unroll
    for (int f = 0; f < 4; ++f) {
        int col = n_base + f * 16 + l15;
        float bv = is_enc ? b1[col] : 0.0f;
        #pragma unroll
        for (int v = 0; v < 4; ++v) {
            int orow = m_base + w * 16 + quad * 4 + v;
            float val = fast_exp2(C2L * (acc[f][v] + bv));
            if (is_enc) Ep[(size_t)orow * 1024 + col] = (_Float16)val;
            else        Dp[(size_t)(orow - 2048) * 1024 + col] = (_Float16)val;
        }
    }
}

// ---------------------------------------------------------------- main fused
// R4 structure (best measured, 47.8 us): block = 4t x 64u x 128o, 4 waves,
// wave w owns u-rows [16w,16w+16) for all 4t; W2T LDS-staged, double-buffered
// BK=64, one barrier per tile; Ep staged once; Dp direct global (64B/row
// sectors, L2-hot). v5's 8-wave split refuted (bb LDS traffic 2x -> 57 us).
// v6 change: rot keyed on blockIdx.x parity. Co-resident blocks are adjacent
// in bx (grid 64x8); giving them k-phases 8 tiles apart anti-phases their
// barrier drains / tanh bursts / MFMA bursts so each block's compute covers
// the other's stalls. (R2's rot was keyed on by>>2 — a no-op for co-resident
// pairs.) Pure fp32 accumulation reorder; zero instruction cost.
__global__ __launch_bounds__(256, 2) void joint_main(
    const _Float16* __restrict__ Ep,   // [2048][1024]
    const _Float16* __restrict__ Dp,   // [512][1024]
    const _Float16* __restrict__ W2T,  // [128][1024]
    const float* __restrict__ b2,      // [128]
    float* __restrict__ out)           // [8][256][64][128]
{
    __shared__ _Float16 sB[2][128 * 64];   // 2 x 16 KiB
    __shared__ _Float16 sE[4 * 1024];      // 8 KiB: 4 Ep rows

    int t0 = blockIdx.x * 4, b = blockIdx.y;
    int tid  = threadIdx.x;
    int w    = tid >> 6, lane = tid & 63;
    int quad = lane >> 4, l15 = lane & 15;
    int u0   = w * 16;
    int rot  = (blockIdx.x & 1) << 3;      // anti-phase co-resident blocks

    const _Float16* epB = Ep + (size_t)(b * 256 + t0) * 1024;   // 4 contiguous rows
    const _Float16* dpr = Dp + (size_t)(b * 64 + u0 + l15) * 1024;

    f32x4 acc[4][8] = {};   // [t][o-tile] = 128 AGPRs

    // stage 4 Ep rows (8 KiB, linear both sides): 512 chunks, 2 per thread
    #pragma unroll
    for (int i = 0; i < 2; ++i) {
        int c = i * 256 + tid;
        stage16(epB + c * 8, sE + (i * 256 + (tid & 0xC0)) * 8);
    }
    // stage W2T k-tile 'rot' into buf 0 (1024 chunks of 16B, 4 per thread)
    #pragma unroll
    for (int i = 0; i < 4; ++i) {
        int c = i * 256 + tid;
        int row = c >> 3, kcs = c & 7;
        stage16(W2T + row * 1024 + rot * 64 + ((kcs ^ (row & 7)) << 3),
                &sB[0][(i * 256 + (tid & 0xC0)) * 8]);
    }

    for (int ii = 0; ii < 16; ++ii) {
        int it = (ii + rot) & 15;          // physical k-tile index
        __syncthreads();   // drains stage(ii) — issued one full tile ago (and sE at ii=0)
        if (ii < 15) {
            int kb = (((ii + 1) + rot) & 15) * 64;
            _Float16* dst = sB[(ii + 1) & 1];
            #pragma unroll
            for (int i = 0; i < 4; ++i) {
                int c = i * 256 + tid;
                int row = c >> 3, kcs = c & 7;
                stage16(W2T + row * 1024 + kb + ((kcs ^ (row & 7)) << 3),
                        dst + (i * 256 + (tid & 0xC0)) * 8);
            }
        }
        const _Float16* sb = sB[ii & 1];
        #pragma unroll
        for (int ki2 = 0; ki2 < 2; ++ki2) {
            int k = it * 64 + ki2 * 32 + quad * 8;
            f16x8 d8 = *reinterpret_cast<const f16x8*>(dpr + k);
            f16x8 A[4];
            #pragma unroll
            for (int tt = 0; tt < 4; ++tt) {
                // broadcast ds_read_b128 (same addr per quad group): conflict-free
                f16x8 e = *reinterpret_cast<const f16x8*>(sE + tt * 1024 + k);
                A[tt] = tanh8(e, d8);
            }
            int kc3 = ki2 * 4 + quad;
            int sw  = (kc3 ^ (l15 & 7)) << 3;        // uniform across f
            #pragma unroll
            for (int f = 0; f < 8; ++f) {
                f16x8 bb = *reinterpret_cast<const f16x8*>(
                    sb + (f * 16 + l15) * 64 + sw);
                #pragma unroll
                for (int tt = 0; tt < 4; ++tt)
                    acc[tt][f] = __builtin_amdgcn_mfma_f32_16x16x32_f16(A[tt], bb, acc[tt][f], 0, 0, 0);
            }
        }
    }

    #pragma unroll
    for (int tt = 0; tt < 4; ++tt) {
        float* o = out + (size_t)(b * 256 + t0 + tt) * 64 * 128;
        #pragma unroll
        for (int f = 0; f < 8; ++f) {
            int oc = f * 16 + l15;
            float bv = b2[oc];
            #pragma unroll
            for (int v = 0; v < 4; ++v) {
                int u = u0 + quad * 4 + v;
                o[u * 128 + oc] = acc[tt][f][v] + bv;
            }
        }
    }
}

// ---------------------------------------------------------------- launch
extern "C" void kernel_launch(void* const* d_in, const int* in_sizes, int n_in,
                              void* d_out, int out_size, void* d_ws, size_t ws_size,
                              hipStream_t stream) {
    const float* enc = (const float*)d_in[0]; // [8][256][512]
    const float* dec = (const float*)d_in[1]; // [8][64][512]
    const float* W1  = (const float*)d_in[2]; // [1024][1024]
    const float* b1  = (const float*)d_in[3]; // [1024]
    const float* W2  = (const float*)d_in[4]; // [1024][128]
    const float* b2  = (const float*)d_in[5]; // [128]
    float* out = (float*)d_out;

    char* ws = (char*)d_ws;
    _Float16* W1T = (_Float16*)(ws);                               // 2 MiB
    _Float16* W2T = (_Float16*)(ws + (2u << 20));                  // 256 KiB
    _Float16* EpP = (_Float16*)(ws + (2u << 20) + (256u << 10));   // 4 MiB
    _Float16* DpP = (_Float16*)(ws + (6u << 20) + (256u << 10));   // 1 MiB

    transpose_both<<<dim3(36, 32), dim3(32, 32), 0, stream>>>(W1, W2, W1T, W2T);

    // fused projections + exp2 epilogue: M = 2048 (enc) + 512 (dec)
    proj_exp<<<dim3(16, 40), 256, 0, stream>>>(enc, dec, W1T, b1, EpP, DpP);

    joint_main<<<dim3(64, 8), 256, 0, stream>>>(EpP, DpP, W2T, b2, out);
}